// Round 2
// 462.200 us; speedup vs baseline: 1.0046x; 1.0046x over previous
//
#include <hip/hip_runtime.h>
#include <stdint.h>

// Problem constants
#define NODES   64
#define FDIM    256
#define ODIM    256
#define BGRAPH  4096
#define TROWS   (NODES * BGRAPH)   // 262144

// GEMM tile: full-K A panel, K-stepped B
#define BM 64
#define BN 256
#define BK 32

typedef short  bf16x8  __attribute__((ext_vector_type(8)));
typedef float  floatx4 __attribute__((ext_vector_type(4)));

// RTNE fp32 -> bf16
__device__ inline unsigned short f2bf(float f) {
    unsigned int u = __float_as_uint(f);
    return (unsigned short)((u + 0x7fffu + ((u >> 16) & 1u)) >> 16);
}

// ---------------------------------------------------------------------------
// Kernel 1: W [node][f][o] fp32 -> Wt [node][o][f] bf16, 1/16 folded.
// (unchanged — verified; ~25 MB traffic, ~6 us)
// ---------------------------------------------------------------------------
__global__ __launch_bounds__(256) void transpose_w(const float* __restrict__ W,
                                                   unsigned short* __restrict__ Wt) {
    __shared__ unsigned short t[64][65];
    const int node = blockIdx.y;
    const int tf = (blockIdx.x >> 2) << 6;
    const int to = (blockIdx.x & 3) << 6;
    const int tid = threadIdx.x;
    const float* Wn = W + node * (FDIM * ODIM);
#pragma unroll
    for (int i = 0; i < 16; ++i) {
        int flat = i * 256 + tid;
        int r = flat >> 6, c = flat & 63;
        float v = Wn[(tf + r) * ODIM + (to + c)] * 0.0625f;
        t[c][r] = f2bf(v);
    }
    __syncthreads();
    unsigned short* Wtn = Wt + node * (FDIM * ODIM);
#pragma unroll
    for (int i = 0; i < 16; ++i) {
        int flat = i * 256 + tid;
        int r = flat >> 6, c = flat & 63;
        Wtn[(to + r) * FDIM + (tf + c)] = t[r][c];
    }
}

// ---------------------------------------------------------------------------
// Kernel 2: per-node GEMM, BM=64 x BN=256, full-K A panel in LDS.
// 256 threads = 4 waves (2m x 2n); wave tile 32x128 = 2x8 mfma_16x16x32_bf16.
// Prologue: B(kt=0) via global_load_lds + A panel staged as contiguous 1KB/row
// bursts (each x byte read exactly once, fully coalesced). K-loop stages only
// the 16KB L2-resident B tile per step -> barrier drains no longer gate the
// HBM stream.
// A layout: row stride 256 ushorts (512B), 16B chunk index XOR-swizzled with
// (row&7) -> ds_read_b128 across 16 rows is 2-way (free); no padding, so
// As+Bs = 32KB+32KB = 64KB exactly (fits the 64KB/WG LDS limit).
// ---------------------------------------------------------------------------
__global__ __launch_bounds__(256, 2) void gemm_node(const float* __restrict__ x,
                                                    const unsigned short* __restrict__ Wt,
                                                    float* __restrict__ out) {
    __shared__ __align__(16) unsigned short As[BM * 256];    // 32 KB, full K=256 panel
    __shared__ __align__(16) unsigned short Bs[2][BN * BK];  // 2 x 16 KB

    // XCD-aware decode: blocks sharing a node land on the same XCD (L2 reuse)
    const int bid  = blockIdx.x;            // 0..4095
    const int xcd  = bid & 7;
    const int jj   = bid >> 3;              // 0..511
    const int node = xcd * 8 + (jj & 7);    // 8 nodes per XCD
    const int mblk = jj >> 3;               // 0..63
    const int b0   = mblk * BM;

    const int tid  = threadIdx.x;
    const int lane = tid & 63;
    const int wave = tid >> 6;
    const int wm   = wave >> 1;             // 0..1 -> 32 rows
    const int wn   = wave & 1;              // 0..1 -> 128 cols
    const int l15  = lane & 15;
    const int l4   = lane >> 4;

    const float* xblk = x + ((size_t)b0 * NODES + node) * FDIM;      // + row*16384 + f
    const unsigned short* wt_node = Wt + (size_t)node * (ODIM * FDIM);

    // ---- issue B stage for kt=0 first (cold HBM/L2 latency overlaps A stage) ----
#pragma unroll
    for (int j = 0; j < 4; ++j) {
        const int slot_base = (wave * 4 + j) * 64;
        const int s = slot_base + lane;
        const int o = s >> 2, c = s & 3;
        const int jg = c ^ ((o >> 1) & 3);
        const unsigned short* g = wt_node + (size_t)o * FDIM + jg * 8;
        __builtin_amdgcn_global_load_lds(
            (const __attribute__((address_space(1))) void*)g,
            (__attribute__((address_space(3))) void*)(&Bs[0][slot_base * 8]),
            16, 0, 0);
    }

    // ---- A panel: 64 rows x 1 KB contiguous each; q = i*256+tid: row=q>>6, ch=q&63
    //      each wave reads one full row per iteration -> perfect 1KB bursts.
    //      Store 8B chunk ch at 16B-slot (ch>>1)^(row&7), half (ch&1). ----
#pragma unroll
    for (int i = 0; i < 16; ++i) {
        const int q = i * 256 + tid;
        const int r = q >> 6, ch = q & 63;
        const float4 v = *(const float4*)(xblk + (size_t)r * (NODES * FDIM) + ch * 4);
        ushort4 p;
        p.x = f2bf(v.x); p.y = f2bf(v.y); p.z = f2bf(v.z); p.w = f2bf(v.w);
        const int slot = (ch >> 1) ^ (r & 7);
        *(ushort4*)(&As[r * 256 + slot * 8 + (ch & 1) * 4]) = p;
    }
    __syncthreads();

    floatx4 acc[2][8] = {};

#pragma unroll
    for (int kt = 0; kt < 8; ++kt) {
        const int cur = kt & 1, nxt = cur ^ 1;

        // ---- prefetch B for kt+1 (L2-resident; overlaps this step's compute) ----
        if (kt < 7) {
            const int k1 = (kt + 1) * BK;
#pragma unroll
            for (int j = 0; j < 4; ++j) {
                const int slot_base = (wave * 4 + j) * 64;
                const int s = slot_base + lane;
                const int o = s >> 2, c = s & 3;
                const int jg = c ^ ((o >> 1) & 3);
                const unsigned short* g = wt_node + (size_t)o * FDIM + k1 + jg * 8;
                __builtin_amdgcn_global_load_lds(
                    (const __attribute__((address_space(1))) void*)g,
                    (__attribute__((address_space(3))) void*)(&Bs[nxt][slot_base * 8]),
                    16, 0, 0);
            }
        }

        // ---- fragments ----
        bf16x8 a[2], b[8];
#pragma unroll
        for (int mi = 0; mi < 2; ++mi) {
            const int m = wm * 32 + mi * 16 + l15;
            const int slot = (kt * 4 + l4) ^ (m & 7);
            a[mi] = *(const bf16x8*)(&As[m * 256 + slot * 8]);
        }
#pragma unroll
        for (int ni = 0; ni < 8; ++ni) {
            const int n = wn * 128 + ni * 16 + l15;
            b[ni] = *(const bf16x8*)(&Bs[cur][n * 32 + (l4 ^ ((n >> 1) & 3)) * 8]);
        }

        // ---- MFMA ----
#pragma unroll
        for (int mi = 0; mi < 2; ++mi)
#pragma unroll
            for (int ni = 0; ni < 8; ++ni)
                acc[mi][ni] = __builtin_amdgcn_mfma_f32_16x16x32_bf16(a[mi], b[ni], acc[mi][ni], 0, 0, 0);

        if (kt < 7) __syncthreads();
    }

    // ---- epilogue: C/D layout col = lane&15, row = (lane>>4)*4 + reg ----
    float* outblk = out + ((size_t)b0 * NODES + node) * ODIM;
#pragma unroll
    for (int mi = 0; mi < 2; ++mi) {
        const int row_base = wm * 32 + mi * 16 + l4 * 4;
#pragma unroll
        for (int ni = 0; ni < 8; ++ni) {
            const int col = wn * 128 + ni * 16 + l15;
#pragma unroll
            for (int r = 0; r < 4; ++r) {
                outblk[(size_t)(row_base + r) * (NODES * ODIM) + col] = acc[mi][ni][r];
            }
        }
    }
}

// ---------------------------------------------------------------------------
// Fallback (only if ws too small): fp32 naive.
// ---------------------------------------------------------------------------
__global__ __launch_bounds__(256) void naive_kernel(const float* __restrict__ x,
                                                    const float* __restrict__ W,
                                                    float* __restrict__ out) {
    __shared__ float xs[FDIM];
    const int row = blockIdx.x;
    const int node = row & (NODES - 1);
    const int o = threadIdx.x;
    xs[o] = x[(size_t)row * FDIM + o];
    __syncthreads();
    const float* Wn = W + (size_t)node * FDIM * ODIM;
    float s = 0.f;
#pragma unroll 8
    for (int f = 0; f < FDIM; ++f) s += xs[f] * Wn[(size_t)f * ODIM + o];
    out[(size_t)row * ODIM + o] = s * 0.0625f;
}

extern "C" void kernel_launch(void* const* d_in, const int* in_sizes, int n_in,
                              void* d_out, int out_size, void* d_ws, size_t ws_size,
                              hipStream_t stream) {
    const float* x = (const float*)d_in[0];
    // d_in[1] = batch (int64) — implied by row layout, unused
    const float* W = (const float*)d_in[2];
    float* out = (float*)d_out;

    const size_t wt_bytes = (size_t)NODES * ODIM * FDIM * sizeof(unsigned short); // 8.4 MB
    if (ws_size >= wt_bytes) {
        unsigned short* Wt = (unsigned short*)d_ws;
        transpose_w<<<dim3(16, NODES), 256, 0, stream>>>(W, Wt);
        gemm_node<<<dim3((BGRAPH / BM) * NODES), 256, 0, stream>>>(x, Wt, out);
    } else {
        naive_kernel<<<dim3(TROWS), 256, 0, stream>>>(x, W, out);
    }
}

// Round 3
// 455.626 us; speedup vs baseline: 1.0191x; 1.0144x over previous
//
#include <hip/hip_runtime.h>
#include <stdint.h>

// Problem constants
#define NODES   64
#define FDIM    256
#define ODIM    256
#define BGRAPH  4096
#define TROWS   (NODES * BGRAPH)   // 262144

// GEMM tile: full-K A panel, K-stepped B
#define BM 64
#define BN 256
#define BK 32

typedef short  bf16x8  __attribute__((ext_vector_type(8)));
typedef float  floatx4 __attribute__((ext_vector_type(4)));

// RTNE fp32 -> bf16
__device__ inline unsigned short f2bf(float f) {
    unsigned int u = __float_as_uint(f);
    return (unsigned short)((u + 0x7fffu + ((u >> 16) & 1u)) >> 16);
}

// ---------------------------------------------------------------------------
// Kernel 1: W [node][f][o] fp32 -> Wt [node][o][f] bf16, 1/16 folded.
// (unchanged — verified)
// ---------------------------------------------------------------------------
__global__ __launch_bounds__(256) void transpose_w(const float* __restrict__ W,
                                                   unsigned short* __restrict__ Wt) {
    __shared__ unsigned short t[64][65];
    const int node = blockIdx.y;
    const int tf = (blockIdx.x >> 2) << 6;
    const int to = (blockIdx.x & 3) << 6;
    const int tid = threadIdx.x;
    const float* Wn = W + node * (FDIM * ODIM);
#pragma unroll
    for (int i = 0; i < 16; ++i) {
        int flat = i * 256 + tid;
        int r = flat >> 6, c = flat & 63;
        float v = Wn[(tf + r) * ODIM + (to + c)] * 0.0625f;
        t[c][r] = f2bf(v);
    }
    __syncthreads();
    unsigned short* Wtn = Wt + node * (FDIM * ODIM);
#pragma unroll
    for (int i = 0; i < 16; ++i) {
        int flat = i * 256 + tid;
        int r = flat >> 6, c = flat & 63;
        Wtn[(to + r) * FDIM + (tf + c)] = t[r][c];
    }
}

// ---------------------------------------------------------------------------
// Kernel 2: per-node GEMM, BM=64 x BN=256, full-K A panel in LDS.
// 512 threads = 8 waves (2m x 4n); wave tile 32x64 = 2x4 mfma_16x16x32_bf16.
// Same LDS (exactly 64KB -> 2 blocks/CU) and same verified swizzles as the
// 256-thread version, but 16 waves/CU (4/SIMD) instead of 8: doubles latency
// hiding and de-phases the stage/compute/write phases of resident blocks.
// __launch_bounds__(512,4) caps VGPR at 128 so both blocks stay resident.
// ---------------------------------------------------------------------------
__global__ __launch_bounds__(512, 4) void gemm_node(const float* __restrict__ x,
                                                    const unsigned short* __restrict__ Wt,
                                                    float* __restrict__ out) {
    __shared__ __align__(16) unsigned short As[BM * 256];    // 32 KB, full K=256 panel
    __shared__ __align__(16) unsigned short Bs[2][BN * BK];  // 2 x 16 KB

    // XCD-aware decode: blocks sharing a node land on the same XCD (L2 reuse)
    const int bid  = blockIdx.x;            // 0..4095
    const int xcd  = bid & 7;
    const int jj   = bid >> 3;              // 0..511
    const int node = xcd * 8 + (jj & 7);    // 8 nodes per XCD
    const int mblk = jj >> 3;               // 0..63
    const int b0   = mblk * BM;

    const int tid  = threadIdx.x;
    const int lane = tid & 63;
    const int wave = tid >> 6;              // 0..7
    const int wm   = wave >> 2;             // 0..1 -> 32 rows
    const int wn   = wave & 3;              // 0..3 -> 64 cols
    const int l15  = lane & 15;
    const int l4   = lane >> 4;

    const float* xblk = x + ((size_t)b0 * NODES + node) * FDIM;      // + row*16384 + f
    const unsigned short* wt_node = Wt + (size_t)node * (ODIM * FDIM);

    // ---- issue B stage for kt=0 first (cold HBM/L2 latency overlaps A stage) ----
#pragma unroll
    for (int j = 0; j < 2; ++j) {
        const int slot_base = (wave * 2 + j) * 64;
        const int s = slot_base + lane;
        const int o = s >> 2, c = s & 3;
        const int jg = c ^ ((o >> 1) & 3);
        const unsigned short* g = wt_node + (size_t)o * FDIM + jg * 8;
        __builtin_amdgcn_global_load_lds(
            (const __attribute__((address_space(1))) void*)g,
            (__attribute__((address_space(3))) void*)(&Bs[0][slot_base * 8]),
            16, 0, 0);
    }

    // ---- A panel: 64 rows x 1 KB contiguous each; q = i*512+tid: row=q>>6, ch=q&63
    //      each wave reads one full row per iteration -> perfect 1KB bursts.
    //      Store 8B chunk ch at 16B-slot (ch>>1)^(row&7), half (ch&1). ----
#pragma unroll
    for (int i = 0; i < 8; ++i) {
        const int q = i * 512 + tid;
        const int r = q >> 6, ch = q & 63;
        const float4 v = *(const float4*)(xblk + (size_t)r * (NODES * FDIM) + ch * 4);
        ushort4 p;
        p.x = f2bf(v.x); p.y = f2bf(v.y); p.z = f2bf(v.z); p.w = f2bf(v.w);
        const int slot = (ch >> 1) ^ (r & 7);
        *(ushort4*)(&As[r * 256 + slot * 8 + (ch & 1) * 4]) = p;
    }
    __syncthreads();

    floatx4 acc[2][4] = {};

#pragma unroll
    for (int kt = 0; kt < 8; ++kt) {
        const int cur = kt & 1, nxt = cur ^ 1;

        // ---- prefetch B for kt+1 (L2-resident; overlaps this step's compute) ----
        if (kt < 7) {
            const int k1 = (kt + 1) * BK;
#pragma unroll
            for (int j = 0; j < 2; ++j) {
                const int slot_base = (wave * 2 + j) * 64;
                const int s = slot_base + lane;
                const int o = s >> 2, c = s & 3;
                const int jg = c ^ ((o >> 1) & 3);
                const unsigned short* g = wt_node + (size_t)o * FDIM + k1 + jg * 8;
                __builtin_amdgcn_global_load_lds(
                    (const __attribute__((address_space(1))) void*)g,
                    (__attribute__((address_space(3))) void*)(&Bs[nxt][slot_base * 8]),
                    16, 0, 0);
            }
        }

        // ---- fragments ----
        bf16x8 a[2], b[4];
#pragma unroll
        for (int mi = 0; mi < 2; ++mi) {
            const int m = wm * 32 + mi * 16 + l15;
            const int slot = (kt * 4 + l4) ^ (m & 7);
            a[mi] = *(const bf16x8*)(&As[m * 256 + slot * 8]);
        }
#pragma unroll
        for (int ni = 0; ni < 4; ++ni) {
            const int n = wn * 64 + ni * 16 + l15;
            b[ni] = *(const bf16x8*)(&Bs[cur][n * 32 + (l4 ^ ((n >> 1) & 3)) * 8]);
        }

        // ---- MFMA ----
#pragma unroll
        for (int mi = 0; mi < 2; ++mi)
#pragma unroll
            for (int ni = 0; ni < 4; ++ni)
                acc[mi][ni] = __builtin_amdgcn_mfma_f32_16x16x32_bf16(a[mi], b[ni], acc[mi][ni], 0, 0, 0);

        if (kt < 7) __syncthreads();
    }

    // ---- epilogue: C/D layout col = lane&15, row = (lane>>4)*4 + reg ----
    float* outblk = out + ((size_t)b0 * NODES + node) * ODIM;
#pragma unroll
    for (int mi = 0; mi < 2; ++mi) {
        const int row_base = wm * 32 + mi * 16 + l4 * 4;
#pragma unroll
        for (int ni = 0; ni < 4; ++ni) {
            const int col = wn * 64 + ni * 16 + l15;
#pragma unroll
            for (int r = 0; r < 4; ++r) {
                outblk[(size_t)(row_base + r) * (NODES * ODIM) + col] = acc[mi][ni][r];
            }
        }
    }
}

// ---------------------------------------------------------------------------
// Fallback (only if ws too small): fp32 naive.
// ---------------------------------------------------------------------------
__global__ __launch_bounds__(256) void naive_kernel(const float* __restrict__ x,
                                                    const float* __restrict__ W,
                                                    float* __restrict__ out) {
    __shared__ float xs[FDIM];
    const int row = blockIdx.x;
    const int node = row & (NODES - 1);
    const int o = threadIdx.x;
    xs[o] = x[(size_t)row * FDIM + o];
    __syncthreads();
    const float* Wn = W + (size_t)node * FDIM * ODIM;
    float s = 0.f;
#pragma unroll 8
    for (int f = 0; f < FDIM; ++f) s += xs[f] * Wn[(size_t)f * ODIM + o];
    out[(size_t)row * ODIM + o] = s * 0.0625f;
}

extern "C" void kernel_launch(void* const* d_in, const int* in_sizes, int n_in,
                              void* d_out, int out_size, void* d_ws, size_t ws_size,
                              hipStream_t stream) {
    const float* x = (const float*)d_in[0];
    // d_in[1] = batch (int64) — implied by row layout, unused
    const float* W = (const float*)d_in[2];
    float* out = (float*)d_out;

    const size_t wt_bytes = (size_t)NODES * ODIM * FDIM * sizeof(unsigned short); // 8.4 MB
    if (ws_size >= wt_bytes) {
        unsigned short* Wt = (unsigned short*)d_ws;
        transpose_w<<<dim3(16, NODES), 256, 0, stream>>>(W, Wt);
        gemm_node<<<dim3((BGRAPH / BM) * NODES), 512, 0, stream>>>(x, Wt, out);
    } else {
        naive_kernel<<<dim3(TROWS), 256, 0, stream>>>(x, W, out);
    }
}